// Round 9
// baseline (461.975 us; speedup 1.0000x reference)
//
#include <hip/hip_runtime.h>
#include <hip/hip_bf16.h>

// Problem constants
#define Bn 16
#define Sn 16
#define Ln 64
#define En 512
#define Hn 512
#define Nn 512   // B*2*S packed batch
#define G4 2048  // 4*H

typedef __bf16 bf16x8 __attribute__((ext_vector_type(8)));
typedef float f32x4 __attribute__((ext_vector_type(4)));
typedef unsigned short u16x8 __attribute__((ext_vector_type(8)));
typedef unsigned short u16x4 __attribute__((ext_vector_type(4)));

__device__ __forceinline__ unsigned short f2bf(float f) {
    union { float f; unsigned u; } v; v.f = f;
    unsigned r = v.u + 0x7FFFu + ((v.u >> 16) & 1u);   // RNE
    return (unsigned short)(r >> 16);
}
__device__ __forceinline__ float bf2f(unsigned short u) {
    union { unsigned u; float f; } v; v.u = ((unsigned)u) << 16;
    return v.f;
}
__device__ __forceinline__ float sigmf(float x) {
    return 1.0f / (1.0f + __expf(-x));
}
__device__ __forceinline__ float tanh_fast(float x) {
    x = fminf(fmaxf(x, -15.0f), 15.0f);
    float e = __expf(2.0f * x);
    return (e - 1.0f) / (e + 1.0f);
}

// ---------------------------------------------------------------------------
// ws layout (bytes)
// ---------------------------------------------------------------------------
#define WS_WIHB  0            // Wih bf16 [gcol 2048][k 512], chunk^(gcol&7) swizzle  2MB
#define WS_WHH   2097152      // Whh image [ut 32][grow 64][k 512], chunk^(grow&7)    2MB
#define WS_BSUM  4194304      // fp32 2048
#define WS_HA    4202496      // h bf16 [n 512][k 512], chunk^(n&7) swizzle   512KB
#define WS_HB    4726784      // 512KB
#define WS_C     5251072      // fp32 [n][u] 1MB
#define WS_FEAT  6299648      // 128KB
#define WS_Z1    6430720      // 16KB
#define WS_XBF   6447104      // x bf16 [m 32768][k 512], chunk^(m&7)  32MB
#define WS_XG    40001536     // Xg bf16 [m 32768][ut 32][u15 16][gate 4]  134MB

// prep_w work items
#define WI_CH 131072
#define WH_CH 131072
#define HZ 32768
#define CZ 65536
#define PREPW_TOTAL (WI_CH + WH_CH + 2048 + HZ + CZ)

__global__ __launch_bounds__(256) void prep_w(
    const float* __restrict__ Wih_f, const float* __restrict__ Whh_f,
    const float* __restrict__ bih, const float* __restrict__ bhh,
    unsigned short* __restrict__ Wihb, unsigned short* __restrict__ WhhImg,
    float* __restrict__ bsum, unsigned short* __restrict__ hA,
    float* __restrict__ c0) {
    int i = blockIdx.x * 256 + threadIdx.x;
    if (i < WI_CH) {
        int gcol = i >> 6, ch = i & 63;
        const float* s = Wih_f + (size_t)gcol * 512 + ch * 8;
        u16x8 w;
#pragma unroll
        for (int j = 0; j < 8; ++j) w[j] = f2bf(s[j]);
        *(u16x8*)(Wihb + (size_t)gcol * 512 + (ch ^ (gcol & 7)) * 8) = w;
    } else if (i < WI_CH + WH_CH) {
        int j = i - WI_CH;
        int g4row = j >> 6, ch = j & 63;
        int gate = g4row >> 9, unit = g4row & 511;
        int ut = unit >> 4, grow = gate * 16 + (unit & 15);
        const float* s = Whh_f + (size_t)g4row * 512 + ch * 8;
        u16x8 w;
#pragma unroll
        for (int k = 0; k < 8; ++k) w[k] = f2bf(s[k]);
        *(u16x8*)(WhhImg + ut * 32768 + grow * 512 + (ch ^ (grow & 7)) * 8) = w;
    } else if (i < WI_CH + WH_CH + 2048) {
        int j = i - (WI_CH + WH_CH);
        bsum[j] = bih[j] + bhh[j];
    } else if (i < WI_CH + WH_CH + 2048 + HZ) {
        int j = i - (WI_CH + WH_CH + 2048);
        u16x8 z = {0, 0, 0, 0, 0, 0, 0, 0};
        *(u16x8*)(hA + j * 8) = z;
    } else if (i < PREPW_TOTAL) {
        int j = i - (WI_CH + WH_CH + 2048 + HZ);
        f32x4 z = {0.f, 0.f, 0.f, 0.f};
        *(f32x4*)(c0 + j * 4) = z;
    }
}

// x -> bf16 [m][k] (m = t*512 + n), chunk^(m&7) swizzle.
__global__ __launch_bounds__(256) void prep_x(
    const float* __restrict__ xf, const float* __restrict__ xa,
    unsigned short* __restrict__ Xbf) {
    int j = blockIdx.x * 256 + threadIdx.x;
    int m = j >> 6, k8 = j & 63;
    int t = m >> 9, n = m & 511;
    int bb = n >> 5, rr = n & 31;
    const float* src = ((rr < Sn)
        ? xf + ((size_t)(bb * Sn + rr) * Ln + t) * En
        : xa + ((size_t)(bb * Sn + (rr - Sn)) * Ln + t) * En) + k8 * 8;
    float4 v0 = *(const float4*)src;
    float4 v1 = *(const float4*)(src + 4);
    u16x8 w;
    w[0] = f2bf(v0.x); w[1] = f2bf(v0.y); w[2] = f2bf(v0.z); w[3] = f2bf(v0.w);
    w[4] = f2bf(v1.x); w[5] = f2bf(v1.y); w[6] = f2bf(v1.z); w[7] = f2bf(v1.w);
    *(u16x8*)(Xbf + (size_t)m * 512 + (k8 ^ (m & 7)) * 8) = w;
}

// ---------------------------------------------------------------------------
// Xg = Xbf @ Wih^T : M=32768, N=2048, K=512. 128x128 tile, BK=64.
// XCD-chunked block map; linear staging writes; swizzled images.
// Epilogue writes gate-packed layout [m][ut][u15][gate].
// ---------------------------------------------------------------------------
__global__ __launch_bounds__(256) void xg_gemm(
    const unsigned short* __restrict__ Xbf,
    const unsigned short* __restrict__ Wihb,
    unsigned short* __restrict__ Xg) {
    __shared__ __align__(16) unsigned short As[2][8192];  // [128 rows][64 k]
    __shared__ __align__(16) unsigned short Bs[2][8192];
    const int tid = threadIdx.x;
    const int p = blockIdx.x;
    const int L = (p & 7) * 512 + (p >> 3);   // bijective XCD-chunked map
    const int bx = L >> 4, by = L & 15;
    const size_t m0 = (size_t)bx * 128;
    const int n0 = by * 128;
    const int wv = tid >> 6, lane = tid & 63;
    const int l15 = lane & 15, sel = lane >> 4;
    const int wm = wv >> 1, wn = wv & 1;

    // staging: thread tid <-> LDS byte tid*16 (+r*4096); linear, conflict-free
    const int srow = tid >> 3;        // + r*32
    const int sseg = tid & 7;         // *8 u16
    const unsigned short* asrc = Xbf + (m0 + srow) * 512 + sseg * 8;
    const unsigned short* bsrc = Wihb + (size_t)(n0 + srow) * 512 + sseg * 8;

    f32x4 acc[4][4];
#pragma unroll
    for (int i = 0; i < 4; ++i)
#pragma unroll
        for (int j = 0; j < 4; ++j) acc[i][j] = (f32x4){0.f, 0.f, 0.f, 0.f};

    u16x8 ar[4], br[4];
#pragma unroll
    for (int r = 0; r < 4; ++r) {
        ar[r] = *(const u16x8*)(asrc + (size_t)r * 32 * 512);
        br[r] = *(const u16x8*)(bsrc + (size_t)r * 32 * 512);
    }

#pragma unroll 1
    for (int it = 0; it < 8; ++it) {
        unsigned short* Ac = As[it & 1];
        unsigned short* Bc = Bs[it & 1];
#pragma unroll
        for (int r = 0; r < 4; ++r) {
            *(u16x8*)((char*)Ac + r * 4096 + tid * 16) = ar[r];
            *(u16x8*)((char*)Bc + r * 4096 + tid * 16) = br[r];
        }
        if (it < 7) {
#pragma unroll
            for (int r = 0; r < 4; ++r) {
                ar[r] = *(const u16x8*)(asrc + (size_t)r * 32 * 512 + (it + 1) * 64);
                br[r] = *(const u16x8*)(bsrc + (size_t)r * 32 * 512 + (it + 1) * 64);
            }
        }
        __syncthreads();
#pragma unroll
        for (int ks = 0; ks < 2; ++ks) {
            bf16x8 a[4], b[4];
#pragma unroll
            for (int i = 0; i < 4; ++i) {
                const int arow = wm * 64 + i * 16 + l15;
                a[i] = *(const bf16x8*)(Ac + arow * 64 + (((ks * 4 + sel) ^ (arow & 7)) * 8));
                const int brow = wn * 64 + i * 16 + l15;
                b[i] = *(const bf16x8*)(Bc + brow * 64 + (((ks * 4 + sel) ^ (brow & 7)) * 8));
            }
#pragma unroll
            for (int i = 0; i < 4; ++i)
#pragma unroll
                for (int j = 0; j < 4; ++j)
                    acc[i][j] = __builtin_amdgcn_mfma_f32_16x16x32_bf16(a[i], b[j], acc[i][j], 0, 0, 0);
        }
    }
    // epilogue: gate-packed store. gate = by>>2, ut = (by&3)*8 + wn*4 + j.
    const int gate = by >> 2;
#pragma unroll
    for (int i = 0; i < 4; ++i)
#pragma unroll
        for (int j = 0; j < 4; ++j) {
            const int ut = (by & 3) * 8 + wn * 4 + j;
#pragma unroll
            for (int q = 0; q < 4; ++q) {
                const size_t m = m0 + wm * 64 + i * 16 + sel * 4 + q;
                Xg[m * 2048 + ut * 64 + l15 * 4 + gate] = f2bf(acc[i][j][q]);
            }
        }
}

// ---------------------------------------------------------------------------
// One LSTM step: gates = Xg[t] + h @ Whh^T; cell; h stored swizzled.
// Grid 512 (nt16 x ut32) x 256 thr (4 waves) -> 2 WGs/CU (TLP overlap).
// Wave wn owns gate wn: [32 rows x 16 units]. K=512, BK=64, 8 iters,
// double-buffered LDS + 2-deep register prefetch.
// ---------------------------------------------------------------------------
__global__ __launch_bounds__(256) void lstm_step(
    const unsigned short* __restrict__ WhhImg,
    const unsigned short* __restrict__ Xg, const float* __restrict__ bsum,
    const unsigned short* __restrict__ h_in, unsigned short* __restrict__ h_out,
    float* __restrict__ c, int t) {
    __shared__ __align__(16) char smem[24576];
    // A0 @0 (4K), A1 @4096, B0 @8192 (8K), B1 @16384 (8K); dump overlays 0..8K
    float* dump = (float*)smem;          // [gate 4][row 32][u15 16] f32 = 8KB

    const int tid = threadIdx.x, bid = blockIdx.x;
    const int nt = bid & 15, ut = bid >> 4;   // nt fast: same-nt WGs share XCD
    const int n0 = nt * 32, u0 = ut * 16;
    const int lane = tid & 63, wn = tid >> 6;  // wave = gate
    const int l15 = lane & 15, sel = lane >> 4;

    // staging roles
    const int asrow = tid >> 3, aseg = tid & 7;      // A: 32 rows x 8 segs
    const int bsrow = tid >> 2, bseg = tid & 3;      // B: 64 rows x 4 segs(32B)

    const unsigned short* hsrc = h_in + (size_t)(n0 + asrow) * 512 + aseg * 8;
    const unsigned short* wsrc = WhhImg + ut * 32768 + bsrow * 512 + bseg * 16;

    f32x4 acc0 = (f32x4){0.f, 0.f, 0.f, 0.f};
    f32x4 acc1 = (f32x4){0.f, 0.f, 0.f, 0.f};

    // 2-deep register prefetch
    u16x8 hv[2], w0[2], w1[2];
    hv[0] = *(const u16x8*)(hsrc);
    w0[0] = *(const u16x8*)(wsrc);
    w1[0] = *(const u16x8*)(wsrc + 8);
    hv[1] = *(const u16x8*)(hsrc + 64);
    w0[1] = *(const u16x8*)(wsrc + 64);
    w1[1] = *(const u16x8*)(wsrc + 64 + 8);

#pragma unroll
    for (int it = 0; it < 8; ++it) {
        const int slot = it & 1;
        char* A = smem + slot * 4096;
        char* B = smem + 8192 + slot * 8192;
        *(u16x8*)(A + tid * 16) = hv[slot];
        *(u16x8*)(B + tid * 32) = w0[slot];
        *(u16x8*)(B + tid * 32 + 16) = w1[slot];
        if (it < 6) {
            hv[slot] = *(const u16x8*)(hsrc + (it + 2) * 64);
            w0[slot] = *(const u16x8*)(wsrc + (it + 2) * 64);
            w1[slot] = *(const u16x8*)(wsrc + (it + 2) * 64 + 8);
        }
        __syncthreads();
#pragma unroll
        for (int ks = 0; ks < 2; ++ks) {
            const int ar0 = l15, ar1 = 16 + l15;
            const int br = wn * 16 + l15;
            bf16x8 a0 = *(const bf16x8*)(A + ar0 * 128 + (((ks * 4 + sel) ^ (ar0 & 7)) * 16));
            bf16x8 a1 = *(const bf16x8*)(A + ar1 * 128 + (((ks * 4 + sel) ^ (ar1 & 7)) * 16));
            bf16x8 b  = *(const bf16x8*)(B + br * 128 + (((ks * 4 + sel) ^ (br & 7)) * 16));
            acc0 = __builtin_amdgcn_mfma_f32_16x16x32_bf16(a0, b, acc0, 0, 0, 0);
            acc1 = __builtin_amdgcn_mfma_f32_16x16x32_bf16(a1, b, acc1, 0, 0, 0);
        }
    }
    __syncthreads();   // all LDS reads done before dump overlays A buffers

    // dump: wave wn holds gate wn, rows 0..31 (acc0: 0-15, acc1: 16-31)
#pragma unroll
    for (int q = 0; q < 4; ++q) {
        dump[wn * 512 + (sel * 4 + q) * 16 + l15] = acc0[q];
        dump[wn * 512 + (16 + sel * 4 + q) * 16 + l15] = acc1[q];
    }
    __syncthreads();

    // cell: 512 cells / 256 thr = 2 each; Xg gate-packed u16x4 read
    const int crow = tid >> 4, cj = tid & 15;
    const float bI = bsum[u0 + cj];
    const float bF = bsum[512 + u0 + cj];
    const float bG = bsum[1024 + u0 + cj];
    const float bO = bsum[1536 + u0 + cj];
#pragma unroll
    for (int half = 0; half < 2; ++half) {
        const int r = crow + half * 16;
        const int n = n0 + r;
        const u16x4 xv = *(const u16x4*)(Xg + ((size_t)t * 512 + n) * 2048 + ut * 64 + cj * 4);
        const float gi = dump[0 * 512 + r * 16 + cj] + bf2f(xv[0]) + bI;
        const float gf = dump[1 * 512 + r * 16 + cj] + bf2f(xv[1]) + bF;
        const float gg = dump[2 * 512 + r * 16 + cj] + bf2f(xv[2]) + bG;
        const float go = dump[3 * 512 + r * 16 + cj] + bf2f(xv[3]) + bO;
        const size_t ci = (size_t)n * 512 + u0 + cj;
        const float I = sigmf(gi), F = sigmf(gf);
        const float G = tanh_fast(gg), O = sigmf(go);
        const float cn = F * c[ci] + I * G;
        c[ci] = cn;
        const int chunk = (ut * 2 + (cj >> 3)) ^ (n & 7);
        h_out[(size_t)n * 512 + chunk * 8 + (cj & 7)] = f2bf(O * tanh_fast(cn));
    }
}

// ---------------------------------------------------------------------------
// Head: pool (de-swizzle), fc1, fc2.
// ---------------------------------------------------------------------------
__global__ __launch_bounds__(256) void pool_kernel(
    const unsigned short* __restrict__ hfin, float* __restrict__ feat) {
    const int blk = blockIdx.x;
    const int b = blk >> 1, side = blk & 1;
    const int tid = threadIdx.x;
    for (int u = tid; u < Hn; u += 256) {
        float s = 0.0f, m = -1e30f;
#pragma unroll
        for (int ss = 0; ss < Sn; ++ss) {
            const int n = b * 32 + side * 16 + ss;
            const int chunk = (u >> 3) ^ (n & 7);
            float v = bf2f(hfin[(size_t)n * 512 + chunk * 8 + (u & 7)]);
            s += v;
            m = fmaxf(m, v);
        }
        feat[b * 2048 + side * 1024 + u] = s * (1.0f / 16.0f);
        feat[b * 2048 + side * 1024 + 512 + u] = m;
    }
}

__global__ __launch_bounds__(256) void fc1_kernel(
    const float* __restrict__ feat, const float* __restrict__ fc1w,
    const float* __restrict__ fc1b, float* __restrict__ z1) {
    __shared__ float fs[2048];
    __shared__ float red[256];
    const int b = blockIdx.x >> 4, oc = blockIdx.x & 15;
    const int tid = threadIdx.x;
    for (int k = tid; k < 2048; k += 256) fs[k] = feat[b * 2048 + k];
    __syncthreads();
    const int o = oc * 16 + (tid & 15);
    const int ks = (tid >> 4) * 128;
    const float4* w4 = (const float4*)(fc1w + (size_t)o * 2048 + ks);
    const float* fr = fs + ks;
    float p = 0.0f;
#pragma unroll 8
    for (int k = 0; k < 32; ++k) {
        float4 w = w4[k];
        p += fr[k * 4] * w.x + fr[k * 4 + 1] * w.y +
             fr[k * 4 + 2] * w.z + fr[k * 4 + 3] * w.w;
    }
    red[(tid & 15) * 16 + (tid >> 4)] = p;
    __syncthreads();
    if (tid < 16) {
        float z = fc1b[oc * 16 + tid];
#pragma unroll
        for (int j = 0; j < 16; ++j) z += red[tid * 16 + j];
        z1[b * 256 + oc * 16 + tid] = z;
    }
}

__global__ __launch_bounds__(256) void fc2_kernel(
    const float* __restrict__ z1, const float* __restrict__ fc2w,
    const float* __restrict__ fc2b, float* __restrict__ out) {
    __shared__ float sh[256];
    const int b = blockIdx.x, tid = threadIdx.x;
    sh[tid] = z1[b * 256 + tid] * fc2w[tid];
    __syncthreads();
    for (int s = 128; s > 0; s >>= 1) {
        if (tid < s) sh[tid] += sh[tid + s];
        __syncthreads();
    }
    if (tid == 0) out[b] = sigmf(sh[0] + fc2b[0]);
}

// ---------------------------------------------------------------------------
extern "C" void kernel_launch(void* const* d_in, const int* in_sizes, int n_in,
                              void* d_out, int out_size, void* d_ws, size_t ws_size,
                              hipStream_t stream) {
    const float* xf    = (const float*)d_in[0];
    const float* xa    = (const float*)d_in[1];
    const float* Wih_f = (const float*)d_in[2];
    const float* Whh_f = (const float*)d_in[3];
    const float* bih   = (const float*)d_in[4];
    const float* bhh   = (const float*)d_in[5];
    const float* fc1w  = (const float*)d_in[6];
    const float* fc1b  = (const float*)d_in[7];
    const float* fc2w  = (const float*)d_in[8];
    const float* fc2b  = (const float*)d_in[9];
    float* out = (float*)d_out;

    char* ws = (char*)d_ws;
    unsigned short* Wihb   = (unsigned short*)(ws + WS_WIHB);
    unsigned short* WhhImg = (unsigned short*)(ws + WS_WHH);
    float*          bsum   = (float*)(ws + WS_BSUM);
    unsigned short* hA     = (unsigned short*)(ws + WS_HA);
    unsigned short* hB     = (unsigned short*)(ws + WS_HB);
    float*          cbuf   = (float*)(ws + WS_C);
    float*          feat   = (float*)(ws + WS_FEAT);
    float*          z1     = (float*)(ws + WS_Z1);
    unsigned short* Xbf    = (unsigned short*)(ws + WS_XBF);
    unsigned short* Xg     = (unsigned short*)(ws + WS_XG);

    prep_w<<<dim3((PREPW_TOTAL + 255) / 256), dim3(256), 0, stream>>>(
        Wih_f, Whh_f, bih, bhh, Wihb, WhhImg, bsum, hA, cbuf);
    prep_x<<<dim3(8192), dim3(256), 0, stream>>>(xf, xa, Xbf);

    xg_gemm<<<dim3(4096), dim3(256), 0, stream>>>(Xbf, Wihb, Xg);

    for (int t = 0; t < Ln; ++t) {
        const unsigned short* hin = (t & 1) ? hB : hA;
        unsigned short* hout      = (t & 1) ? hA : hB;
        lstm_step<<<dim3(512), dim3(256), 0, stream>>>(
            WhhImg, Xg, bsum, hin, hout, cbuf, t);
    }
    // t=63 wrote hA
    pool_kernel<<<dim3(32), dim3(256), 0, stream>>>(hA, feat);
    fc1_kernel<<<dim3(256), dim3(256), 0, stream>>>(feat, fc1w, fc1b, z1);
    fc2_kernel<<<dim3(16), dim3(256), 0, stream>>>(z1, fc2w, fc2b, out);
}